// Round 1
// baseline (805.579 us; speedup 1.0000x reference)
//
#include <hip/hip_runtime.h>
#include <cstdint>
#include <cstddef>

#define DM 1024
#define B_SZ 256
#define L_SZ 65
#define H_SZ 16
#define M_ROWS 16640   // B*L
#define VOCAB 129

typedef __attribute__((ext_vector_type(8))) short bf16x8;
typedef __attribute__((ext_vector_type(4))) float f32x4;
typedef unsigned short u16t;
typedef unsigned int   u32t;

__device__ __forceinline__ u16t f2bf(float x){
  u32t u = __builtin_bit_cast(u32t, x);
  u = u + 0x7FFFu + ((u >> 16) & 1u);   // RNE
  return (u16t)(u >> 16);
}

__device__ __forceinline__ f32x4 mfma16(bf16x8 a, bf16x8 b, f32x4 c){
  return __builtin_amdgcn_mfma_f32_16x16x32_bf16(a, b, c, 0, 0, 0);
}

__device__ __forceinline__ void gload_lds16(const void* g, void* l){
  __builtin_amdgcn_global_load_lds(
      (const __attribute__((address_space(1))) unsigned int*)g,
      (__attribute__((address_space(3))) unsigned int*)l, 16, 0, 0);
}

// ---------------- cast f32 -> bf16 (vectorized) ----------------
__global__ void rmha_cast(const float* __restrict__ in, u16t* __restrict__ out, int n4){
  int i = blockIdx.x*blockDim.x + threadIdx.x;
  const int stride = gridDim.x*blockDim.x;
  for (; i < n4; i += stride){
    float4 v = reinterpret_cast<const float4*>(in)[i];
    ushort4 o;
    o.x = f2bf(v.x); o.y = f2bf(v.y); o.z = f2bf(v.z); o.w = f2bf(v.w);
    reinterpret_cast<ushort4*>(out)[i] = o;
  }
}

// ---------------- weight transpose-cast: Wt[n][k] = bf16(W[k][n]) ----------------
__global__ void rmha_tcast_w(const float* __restrict__ W, u16t* __restrict__ Wt){
  __shared__ float tile[64][65];
  const int t = blockIdx.x;
  const int k0 = (t >> 4) << 6, n0 = (t & 15) << 6;
  const int tr = threadIdx.x >> 6, tc = threadIdx.x & 63;
  #pragma unroll
  for (int rr = 0; rr < 64; rr += 4)
    tile[rr + tr][tc] = W[(size_t)(k0 + rr + tr)*DM + n0 + tc];
  __syncthreads();
  #pragma unroll
  for (int rr = 0; rr < 64; rr += 4)
    Wt[(size_t)(n0 + rr + tr)*DM + k0 + tc] = f2bf(tile[tc][rr + tr]);
}

// ---------------- rel tables: relkP[144][64] (rows>=129 zero), relvT[64][160] (cols>=129 zero) ----------------
__global__ void rmha_build_rel(const float* __restrict__ rk, const float* __restrict__ rv,
                               u16t* __restrict__ relkP, u16t* __restrict__ relvT){
  const int tid = blockIdx.x*blockDim.x + threadIdx.x;
  const int stride = gridDim.x*blockDim.x;
  for (int i = tid; i < 144*64; i += stride){
    int j = i >> 6, d = i & 63;
    relkP[i] = (j < VOCAB) ? f2bf(rk[j*64 + d]) : (u16t)0;
  }
  for (int i = tid; i < 64*160; i += stride){
    int d = i / 160, j = i - d*160;
    relvT[i] = (j < VOCAB) ? f2bf(rv[j*64 + d]) : (u16t)0;
  }
}

// ---------------- 128x128xK GEMM, bf16 MFMA, m97-style ----------------
// A: [16640][1024] bf16 row-major.  Bt: [1024][1024] bf16 = W^T (Bt[n][k]).
// LDS layout per tile: [kc(2)][g(4)][row(128)][8 bf16] -> linear gload_lds dest,
// conflict-free ds_read_b128 fragment reads.
template<bool OUTF32>
__global__ __launch_bounds__(256) void rmha_gemm(
    const u16t* __restrict__ A, const u16t* __restrict__ Bt, void* __restrict__ Cout)
{
  __shared__ __attribute__((aligned(16))) u16t As[8192];
  __shared__ __attribute__((aligned(16))) u16t Bs[8192];
  const int tid = threadIdx.x;
  const int lane = tid & 63, wave = tid >> 6;
  const int g = lane >> 4, r16 = lane & 15;
  const int bid = blockIdx.x;
  const int bm = bid >> 3, bn = bid & 7;     // bn fastest: 8 N-blocks share A panel
  const int m0 = bm << 7, n0 = bn << 7;
  const int wm = wave >> 1, wn = wave & 1;

  f32x4 acc[4][4];
  #pragma unroll
  for (int mt = 0; mt < 4; ++mt)
    #pragma unroll
    for (int nt = 0; nt < 4; ++nt)
      acc[mt][nt] = (f32x4){0.f,0.f,0.f,0.f};

  for (int kt = 0; kt < 16; ++kt){
    __syncthreads();                                   // prev compute done
    #pragma unroll
    for (int it = 0; it < 4; ++it){
      int idx = it*256 + tid;
      int kc = idx >> 9, gg = (idx >> 7) & 3, mm = idx & 127;
      int soff = (kt << 6) + (kc << 5) + (gg << 3);
      gload_lds16(A  + (size_t)(m0 + mm)*DM + soff, As + (size_t)(it*256 + wave*64)*8);
      gload_lds16(Bt + (size_t)(n0 + mm)*DM + soff, Bs + (size_t)(it*256 + wave*64)*8);
    }
    __syncthreads();                                   // stage visible (drains vmcnt)
    #pragma unroll
    for (int kc = 0; kc < 2; ++kc){
      bf16x8 a[4], b[4];
      #pragma unroll
      for (int mt = 0; mt < 4; ++mt)
        a[mt] = *reinterpret_cast<const bf16x8*>(As + ((size_t)((kc*4 + g)*128) + wm*64 + mt*16 + r16)*8);
      #pragma unroll
      for (int nt = 0; nt < 4; ++nt)
        b[nt] = *reinterpret_cast<const bf16x8*>(Bs + ((size_t)((kc*4 + g)*128) + wn*64 + nt*16 + r16)*8);
      #pragma unroll
      for (int mt = 0; mt < 4; ++mt)
        #pragma unroll
        for (int nt = 0; nt < 4; ++nt)
          acc[mt][nt] = mfma16(a[mt], b[nt], acc[mt][nt]);
    }
  }
  #pragma unroll
  for (int mt = 0; mt < 4; ++mt){
    int row0 = m0 + wm*64 + mt*16 + g*4;
    #pragma unroll
    for (int nt = 0; nt < 4; ++nt){
      int col = n0 + wn*64 + nt*16 + r16;
      #pragma unroll
      for (int rq = 0; rq < 4; ++rq){
        if (OUTF32) reinterpret_cast<float*>(Cout)[(size_t)(row0 + rq)*DM + col] = acc[mt][nt][rq];
        else        reinterpret_cast<u16t*>(Cout)[(size_t)(row0 + rq)*DM + col] = f2bf(acc[mt][nt][rq]);
      }
    }
  }
}

// ---------------- fused relative attention ----------------
// 1 block = 1 (b,h); 5 waves = 5 row-tiles of 16 (rows 0..79, valid < 65).
#define VT_W 104          // V^T LDS row width (u16), stride 208B: 2-way banks, 16B aligned
#define PBW  248          // P buffer width (u16), stride 496B: 2-way banks; [64 zero | 80 P | zero]
#define QRW  148          // QR buffer width (f32), stride 592B
#define WBUF_B 9472       // per-wave union buffer: max(16*QRW*4, 16*PBW*2) = 9472

__global__ __launch_bounds__(320) void rmha_attn(
    const u16t* __restrict__ Qp, const u16t* __restrict__ Kp, const u16t* __restrict__ Vp,
    const u16t* __restrict__ relkP, const u16t* __restrict__ relvT,
    u16t* __restrict__ Og)
{
  __shared__ __attribute__((aligned(16))) u16t Vt[64*VT_W];
  __shared__ __attribute__((aligned(16))) char wbufA[5*WBUF_B];
  const int tid = threadIdx.x;
  const int bid = blockIdx.x;
  const int b = bid >> 4, h = bid & 15;
  const size_t bh = (size_t)b*L_SZ*DM + (size_t)h*64;

  // stage V^T into LDS (valid rows 0..64), zero cols 65..103
  for (int c = tid; c < 520; c += 320){                // 65*64/8 chunks
    int r = c >> 3, d0 = (c & 7) << 3;
    const u16t* src = Vp + bh + (size_t)r*DM + d0;
    ushort4 v0 = *reinterpret_cast<const ushort4*>(src);
    ushort4 v1 = *reinterpret_cast<const ushort4*>(src + 4);
    Vt[(d0+0)*VT_W + r] = v0.x; Vt[(d0+1)*VT_W + r] = v0.y;
    Vt[(d0+2)*VT_W + r] = v0.z; Vt[(d0+3)*VT_W + r] = v0.w;
    Vt[(d0+4)*VT_W + r] = v1.x; Vt[(d0+5)*VT_W + r] = v1.y;
    Vt[(d0+6)*VT_W + r] = v1.z; Vt[(d0+7)*VT_W + r] = v1.w;
  }
  for (int i = tid; i < 64*(VT_W-65); i += 320){
    int d = i / (VT_W-65), r = 65 + (i - d*(VT_W-65));
    Vt[d*VT_W + r] = 0;
  }
  __syncthreads();

  const int wave = tid >> 6, lane = tid & 63;
  const int g = lane >> 4, r16 = lane & 15;
  char* wbuf = wbufA + wave*WBUF_B;
  float* qrb = reinterpret_cast<float*>(wbuf);
  u16t*  pb  = reinterpret_cast<u16t*>(wbuf);

  // Q A-fragments for this row-tile (rows l = 16*wave + r16)
  const int lrow = wave*16 + r16;
  bf16x8 qf[2];
  #pragma unroll
  for (int kc = 0; kc < 2; ++kc)
    qf[kc] = *reinterpret_cast<const bf16x8*>(Qp + bh + (size_t)lrow*DM + kc*32 + g*8);

  // QR = Q @ relk^T  -> wave-private LDS [16][QRW] f32
  #pragma unroll
  for (int nt = 0; nt < 9; ++nt){
    int j = nt*16 + r16;
    f32x4 qr = (f32x4){0.f,0.f,0.f,0.f};
    #pragma unroll
    for (int kc = 0; kc < 2; ++kc){
      bf16x8 bb = *reinterpret_cast<const bf16x8*>(relkP + (size_t)j*64 + kc*32 + g*8);
      qr = mfma16(qf[kc], bb, qr);
    }
    #pragma unroll
    for (int rq = 0; rq < 4; ++rq)
      qrb[(g*4 + rq)*QRW + j] = qr[rq];
  }
  asm volatile("s_waitcnt lgkmcnt(0)" ::: "memory");

  // init S with skewed QR: S[l][r] = QR[l][r-l+64]
  f32x4 s[5];
  #pragma unroll
  for (int nt = 0; nt < 5; ++nt){
    #pragma unroll
    for (int rq = 0; rq < 4; ++rq){
      int ml = g*4 + rq;
      int j = (nt*16 + r16) - (wave*16 + ml) + 64;   // always in [0,128] for valid l,r
      j = j < 0 ? 0 : j;                             // pad rows only
      s[nt][rq] = qrb[ml*QRW + j];
    }
  }
  asm volatile("" ::: "memory");

  // S += Q K^T (B-fragments straight from global K rows)
  #pragma unroll
  for (int kc = 0; kc < 2; ++kc){
    #pragma unroll
    for (int nt = 0; nt < 5; ++nt){
      bf16x8 kb = *reinterpret_cast<const bf16x8*>(Kp + bh + (size_t)(nt*16 + r16)*DM + kc*32 + g*8);
      s[nt] = mfma16(qf[kc], kb, s[nt]);
    }
  }

  // scale + mask cols >= 65, softmax over the 80-col row (16 lanes x 5 frags)
  float mx[4] = {-3e38f,-3e38f,-3e38f,-3e38f};
  #pragma unroll
  for (int nt = 0; nt < 5; ++nt){
    bool valid = (nt*16 + r16) < 65;
    #pragma unroll
    for (int rq = 0; rq < 4; ++rq){
      float v = valid ? s[nt][rq]*0.125f : -3e38f;
      s[nt][rq] = v;
      mx[rq] = fmaxf(mx[rq], v);
    }
  }
  #pragma unroll
  for (int rq = 0; rq < 4; ++rq){
    float m = mx[rq];
    m = fmaxf(m, __shfl_xor(m, 1));
    m = fmaxf(m, __shfl_xor(m, 2));
    m = fmaxf(m, __shfl_xor(m, 4));
    m = fmaxf(m, __shfl_xor(m, 8));
    mx[rq] = m;
  }
  float sum[4] = {0.f,0.f,0.f,0.f};
  #pragma unroll
  for (int nt = 0; nt < 5; ++nt)
    #pragma unroll
    for (int rq = 0; rq < 4; ++rq){
      float p = __expf(s[nt][rq] - mx[rq]);
      s[nt][rq] = p;                         // unnormalized P
      sum[rq] += p;
    }
  #pragma unroll
  for (int rq = 0; rq < 4; ++rq){
    float t = sum[rq];
    t += __shfl_xor(t, 1);
    t += __shfl_xor(t, 2);
    t += __shfl_xor(t, 4);
    t += __shfl_xor(t, 8);
    sum[rq] = t;
  }

  // zero the whole wave buffer (QR dead), then write P at col offset 64+r
  #pragma unroll
  for (int i = 0; i < 10; ++i){
    int o16 = i*64 + lane;                   // 592 16B-chunks total
    if (o16 < WBUF_B/16) reinterpret_cast<uint4*>(wbuf)[o16] = make_uint4(0,0,0,0);
  }
  asm volatile("" ::: "memory");
  #pragma unroll
  for (int nt = 0; nt < 5; ++nt){
    int r = nt*16 + r16;
    #pragma unroll
    for (int rq = 0; rq < 4; ++rq)
      pb[(g*4 + rq)*PBW + 64 + r] = f2bf(s[nt][rq]);
  }
  asm volatile("s_waitcnt lgkmcnt(0)" ::: "memory");

  // O = P @ V  (V^T in LDS)
  f32x4 o[4];
  #pragma unroll
  for (int nt = 0; nt < 4; ++nt) o[nt] = (f32x4){0.f,0.f,0.f,0.f};
  #pragma unroll
  for (int kc = 0; kc < 3; ++kc){            // r = 0..95 (>=65 contributes 0)
    bf16x8 af = *reinterpret_cast<const bf16x8*>(pb + (size_t)r16*PBW + 64 + kc*32 + g*8);
    #pragma unroll
    for (int nt = 0; nt < 4; ++nt){
      bf16x8 bv = *reinterpret_cast<const bf16x8*>(Vt + (size_t)(nt*16 + r16)*VT_W + kc*32 + g*8);
      o[nt] = mfma16(af, bv, o[nt]);
    }
  }
  // O += Pr @ relv : Pr[l][j] = P[l][l+j-64] ; buffer index = l + j (zero outside window)
  #pragma unroll
  for (int kc = 0; kc < 5; ++kc){            // j = 0..159 (>=129 contributes 0 via relvT pad)
    bf16x8 af;
    int base = r16*PBW + (wave*16 + r16) + kc*32 + g*8;
    #pragma unroll
    for (int i = 0; i < 8; ++i)
      af[i] = (short)pb[base + i];
    #pragma unroll
    for (int nt = 0; nt < 4; ++nt){
      bf16x8 bv = *reinterpret_cast<const bf16x8*>(relvT + (size_t)(nt*16 + r16)*160 + kc*32 + g*8);
      o[nt] = mfma16(af, bv, o[nt]);
    }
  }
  // normalize (deferred softmax denom) + store bf16 heads output [B,L,H*D]
  #pragma unroll
  for (int rq = 0; rq < 4; ++rq){
    int l = wave*16 + g*4 + rq;
    float inv = 1.0f / sum[rq];
    if (l < 65){
      #pragma unroll
      for (int nt = 0; nt < 4; ++nt)
        Og[((size_t)b*L_SZ + l)*DM + h*64 + nt*16 + r16] = f2bf(o[nt][rq]*inv);
    }
  }
}

// ---------------- host launcher ----------------
extern "C" void kernel_launch(void* const* d_in, const int* in_sizes, int n_in,
                              void* d_out, int out_size, void* d_ws, size_t ws_size,
                              hipStream_t stream)
{
  const float* q  = (const float*)d_in[0];
  const float* k  = (const float*)d_in[1];
  const float* v  = (const float*)d_in[2];
  const float* Wq = (const float*)d_in[3];
  const float* Wk = (const float*)d_in[4];
  const float* Wv = (const float*)d_in[5];
  const float* Wo = (const float*)d_in[6];
  const float* rk = (const float*)d_in[7];
  const float* rv = (const float*)d_in[8];

  const size_t NE = (size_t)M_ROWS*DM;      // 17,039,360 elements

  // d_out (f32, 68MB) doubles as scratch for the two bf16 cast buffers
  u16t* qb = (u16t*)d_out;
  u16t* kb = qb + NE;

  char* w = (char*)d_ws;
  size_t off = 0;
  auto nxt = [&](size_t bytes)->char* {
    char* p = w + off; off += (bytes + 255) & ~(size_t)255; return p;
  };
  u16t* vb    = (u16t*)nxt(NE*2);            // later reused as Og
  u16t* Qp    = (u16t*)nxt(NE*2 + 32768);    // slack: attn reads pad rows
  u16t* Kp    = (u16t*)nxt(NE*2 + 32768);
  u16t* Vp    = (u16t*)nxt(NE*2);
  u16t* Wtq   = (u16t*)nxt((size_t)DM*DM*2);
  u16t* Wtk   = (u16t*)nxt((size_t)DM*DM*2);
  u16t* Wtv   = (u16t*)nxt((size_t)DM*DM*2);
  u16t* Wto   = (u16t*)nxt((size_t)DM*DM*2);
  u16t* relkP = (u16t*)nxt(144*64*2);
  u16t* relvT = (u16t*)nxt(64*160*2);
  u16t* Og    = vb;                          // vb dead after V-projection GEMM

  const int n4 = (int)(NE/4);
  rmha_cast<<<2048,256,0,stream>>>(q, qb, n4);
  rmha_cast<<<2048,256,0,stream>>>(k, kb, n4);
  rmha_cast<<<2048,256,0,stream>>>(v, vb, n4);
  rmha_tcast_w<<<256,256,0,stream>>>(Wq, Wtq);
  rmha_tcast_w<<<256,256,0,stream>>>(Wk, Wtk);
  rmha_tcast_w<<<256,256,0,stream>>>(Wv, Wtv);
  rmha_tcast_w<<<256,256,0,stream>>>(Wo, Wto);
  rmha_build_rel<<<64,256,0,stream>>>(rk, rv, relkP, relvT);

  rmha_gemm<false><<<1040,256,0,stream>>>(qb, Wtq, Qp);
  rmha_gemm<false><<<1040,256,0,stream>>>(kb, Wtk, Kp);
  rmha_gemm<false><<<1040,256,0,stream>>>(vb, Wtv, Vp);

  rmha_attn<<<4096,320,0,stream>>>(Qp, Kp, Vp, relkP, relvT, Og);

  rmha_gemm<true><<<1040,256,0,stream>>>(Og, Wto, d_out);
}